// Round 8
// baseline (40.433 us; speedup 1.0000x reference)
//
#include <hip/hip_runtime.h>
#include <stdint.h>

#define TOKENS 32768
#define IN_F   512
#define OUT_F  512
#define KW     16          // 512 bits -> 16 u32 words per row

typedef float f32x4 __attribute__((ext_vector_type(4)));

// ---------------------------------------------------------------------------
// Bit-packing permutation (identical in both kernels, so XOR+popc dot
// products are unaffected): from a row read as float4[128] (index f, lane l),
// word k = f_hi*8 + c*2 + h holds in bit l the sign of float4 #(f_hi*64+l)
// element c (h selects lanes 0..31 / 32..63).
// ---------------------------------------------------------------------------

// Kernel A: binarize weight (minus per-row threshold) into transposed
// bit-plane layout wbT[k][o]. One wave per output row o.
__global__ __launch_bounds__(256) void binw_kernel(
    const float* __restrict__ w,      // [OUT_F][IN_F]
    const float* __restrict__ thr,    // [OUT_F]
    uint32_t* __restrict__ wbT)       // [KW][OUT_F]
{
    const int o    = (blockIdx.x * 256 + threadIdx.x) >> 6;  // 512 waves total
    const int lane = threadIdx.x & 63;

    const float t = thr[o];
    const float4* wr = (const float4*)(w + (size_t)o * IN_F);
#pragma unroll
    for (int j = 0; j < 2; ++j) {
        float4 v = wr[j * 64 + lane];
        float vals[4] = {v.x - t, v.y - t, v.z - t, v.w - t};
#pragma unroll
        for (int c = 0; c < 4; ++c) {
            unsigned long long m = __ballot(vals[c] >= 0.0f);
            if (lane == 0) {
                wbT[(j * 8 + c * 2 + 0) * OUT_F + o] = (uint32_t)m;
                wbT[(j * 8 + c * 2 + 1) * OUT_F + o] = (uint32_t)(m >> 32);
            }
        }
    }
}

// ---------------------------------------------------------------------------
// Kernel B: fused binarize-x + binary GEMM, weight bits resident in VGPRs
// (round-4 structure). 2048 blocks x 4 waves; wave gw owns og = gw&1
// (256 cols, lane -> 4 cols) and rows row_base + j*4096, j=0..7
// (row_base = gw>>1 in [0,4096)). Depth-2 prefetch. Non-temporal LOADS for
// x (no L2 reuse beyond same-CU L1) keep L2 free for the out write stream;
// non-temporal stores for out.
// ---------------------------------------------------------------------------
__global__ __launch_bounds__(256, 4) void bgemm_kernel(
    const float*    __restrict__ x,     // [TOKENS][IN_F]
    const uint32_t* __restrict__ wbT,   // [KW][OUT_F]
    const float*    __restrict__ shift, // [1]
    float*          __restrict__ out)   // [TOKENS][OUT_F]
{
    const int lane = threadIdx.x & 63;
    const int wid  = threadIdx.x >> 6;
    const int gw   = blockIdx.x * 4 + wid;      // 0..8191
    const int og   = gw & 1;
    const int row_base = gw >> 1;               // 0..4095

    // --- weight bits for this wave's 256 columns: 64 VGPRs, loaded once ---
    uint32_t wv[KW][4];
    const uint32_t* wp = wbT + og * 256 + lane * 4;
#pragma unroll
    for (int k = 0; k < KW; ++k) {
        uint4 v = *(const uint4*)(wp + k * OUT_F);
        wv[k][0] = v.x; wv[k][1] = v.y; wv[k][2] = v.z; wv[k][3] = v.w;
    }

    // scale = 2^round(clip(shift, -8, 0)), round-half-even == rintf
    float s = shift[0];
    s = fminf(fmaxf(s, -8.0f), 0.0f);
    const float scale   = exp2f(rintf(s));
    const float negtwos = -2.0f * scale;
    const float basev   = (float)IN_F * scale;

    const f32x4* xr = (const f32x4*)x;

    // two row slots in flight (depth-2 prefetch), non-temporal loads
    f32x4 a[2][2];
    {
        const size_t rb0 = (size_t)row_base * 128;
        const size_t rb1 = (size_t)(row_base + 4096) * 128;
        a[0][0] = __builtin_nontemporal_load(xr + rb0 + lane);
        a[0][1] = __builtin_nontemporal_load(xr + rb0 + 64 + lane);
        a[1][0] = __builtin_nontemporal_load(xr + rb1 + lane);
        a[1][1] = __builtin_nontemporal_load(xr + rb1 + 64 + lane);
    }

#pragma unroll
    for (int j = 0; j < 8; ++j) {
        const int slot = j & 1;
        const int row  = row_base + j * 4096;

        // 1) ballot-pack row j -> wave-uniform words (frees slot's VGPRs)
        uint32_t xw[KW];
        {
            unsigned long long m;
            m = __ballot(a[slot][0].x >= 0.0f); xw[0]  = (uint32_t)m; xw[1]  = (uint32_t)(m >> 32);
            m = __ballot(a[slot][0].y >= 0.0f); xw[2]  = (uint32_t)m; xw[3]  = (uint32_t)(m >> 32);
            m = __ballot(a[slot][0].z >= 0.0f); xw[4]  = (uint32_t)m; xw[5]  = (uint32_t)(m >> 32);
            m = __ballot(a[slot][0].w >= 0.0f); xw[6]  = (uint32_t)m; xw[7]  = (uint32_t)(m >> 32);
            m = __ballot(a[slot][1].x >= 0.0f); xw[8]  = (uint32_t)m; xw[9]  = (uint32_t)(m >> 32);
            m = __ballot(a[slot][1].y >= 0.0f); xw[10] = (uint32_t)m; xw[11] = (uint32_t)(m >> 32);
            m = __ballot(a[slot][1].z >= 0.0f); xw[12] = (uint32_t)m; xw[13] = (uint32_t)(m >> 32);
            m = __ballot(a[slot][1].w >= 0.0f); xw[14] = (uint32_t)m; xw[15] = (uint32_t)(m >> 32);
        }

        // 2) issue depth-2 prefetch of row j+2 into the freed slot
        if (j < 6) {
            const size_t nb = (size_t)(row + 2 * 4096) * 128;
            a[slot][0] = __builtin_nontemporal_load(xr + nb + lane);
            a[slot][1] = __builtin_nontemporal_load(xr + nb + 64 + lane);
        }

        // 3) XOR + popcount accumulate (wave-uniform xw vs per-lane wv)
        uint32_t acc0 = 0, acc1 = 0, acc2 = 0, acc3 = 0;
#pragma unroll
        for (int k = 0; k < KW; ++k) {
            acc0 += __popc(xw[k] ^ wv[k][0]);
            acc1 += __popc(xw[k] ^ wv[k][1]);
            acc2 += __popc(xw[k] ^ wv[k][2]);
            acc3 += __popc(xw[k] ^ wv[k][3]);
        }

        // 4) (512 - 2*acc) * scale, exact in fp32; non-temporal store
        f32x4 o4;
        o4.x = fmaf(negtwos, (float)acc0, basev);
        o4.y = fmaf(negtwos, (float)acc1, basev);
        o4.z = fmaf(negtwos, (float)acc2, basev);
        o4.w = fmaf(negtwos, (float)acc3, basev);
        __builtin_nontemporal_store(o4,
            (f32x4*)&out[(size_t)row * OUT_F + og * 256 + lane * 4]);
    }
}

extern "C" void kernel_launch(void* const* d_in, const int* in_sizes, int n_in,
                              void* d_out, int out_size, void* d_ws, size_t ws_size,
                              hipStream_t stream) {
    const float* x     = (const float*)d_in[0];
    const float* w     = (const float*)d_in[1];
    const float* thr   = (const float*)d_in[2];
    const float* shift = (const float*)d_in[3];
    float*       out   = (float*)d_out;
    uint32_t*    wbT   = (uint32_t*)d_ws;   // 16*512*4 = 32 KB scratch

    binw_kernel<<<128, 256, 0, stream>>>(w, thr, wbT);
    bgemm_kernel<<<2048, 256, 0, stream>>>(x, wbT, shift, out);
}

// Round 9
// 34.953 us; speedup vs baseline: 1.1568x; 1.1568x over previous
//
#include <hip/hip_runtime.h>
#include <stdint.h>

#define TOKENS 32768
#define IN_F   512
#define OUT_F  512
#define KW     16          // 512 bits -> 16 u32 words per row

typedef float f32x4 __attribute__((ext_vector_type(4)));

// ---------------------------------------------------------------------------
// Bit-packing permutation (identical in both kernels, so XOR+popc dot
// products are unaffected): from a row read as float4[128] (index f, lane l),
// word k = f_hi*8 + c*2 + h holds in bit l the sign of float4 #(f_hi*64+l)
// element c (h selects lanes 0..31 / 32..63).
// ---------------------------------------------------------------------------

// Kernel A: binarize weight (minus per-row threshold) into transposed
// bit-plane layout wbT[k][o]. One wave per output row o.
__global__ __launch_bounds__(256) void binw_kernel(
    const float* __restrict__ w,      // [OUT_F][IN_F]
    const float* __restrict__ thr,    // [OUT_F]
    uint32_t* __restrict__ wbT)       // [KW][OUT_F]
{
    const int o    = (blockIdx.x * 256 + threadIdx.x) >> 6;  // 512 waves total
    const int lane = threadIdx.x & 63;

    const float t = thr[o];
    const float4* wr = (const float4*)(w + (size_t)o * IN_F);
#pragma unroll
    for (int j = 0; j < 2; ++j) {
        float4 v = wr[j * 64 + lane];
        float vals[4] = {v.x - t, v.y - t, v.z - t, v.w - t};
#pragma unroll
        for (int c = 0; c < 4; ++c) {
            unsigned long long m = __ballot(vals[c] >= 0.0f);
            if (lane == 0) {
                wbT[(j * 8 + c * 2 + 0) * OUT_F + o] = (uint32_t)m;
                wbT[(j * 8 + c * 2 + 1) * OUT_F + o] = (uint32_t)(m >> 32);
            }
        }
    }
}

// ---------------------------------------------------------------------------
// Kernel B: fused binarize-x + binary GEMM, weight bits resident in VGPRs.
// Round-4 structure EXACTLY except plain (cached) stores instead of
// non-temporal — isolating the NT-store toggle. Wave gw owns og = gw&1
// (256 cols, lane -> 4 cols) and rows row_base + j*2048, j=0..15.
// Depth-2 prefetch: pack row j into SGPR words (freeing its register slot),
// then issue the row j+2 load into that slot.
// ---------------------------------------------------------------------------
__global__ __launch_bounds__(256, 4) void bgemm_kernel(
    const float*    __restrict__ x,     // [TOKENS][IN_F]
    const uint32_t* __restrict__ wbT,   // [KW][OUT_F]
    const float*    __restrict__ shift, // [1]
    float*          __restrict__ out)   // [TOKENS][OUT_F]
{
    const int lane = threadIdx.x & 63;
    const int wid  = threadIdx.x >> 6;
    const int gw   = blockIdx.x * 4 + wid;      // 0..4095
    const int og   = gw & 1;
    const int row_base = gw >> 1;               // 0..2047

    // --- weight bits for this wave's 256 columns: 64 VGPRs, loaded once ---
    uint32_t wv[KW][4];
    const uint32_t* wp = wbT + og * 256 + lane * 4;
#pragma unroll
    for (int k = 0; k < KW; ++k) {
        uint4 v = *(const uint4*)(wp + k * OUT_F);
        wv[k][0] = v.x; wv[k][1] = v.y; wv[k][2] = v.z; wv[k][3] = v.w;
    }

    // scale = 2^round(clip(shift, -8, 0)), round-half-even == rintf
    float s = shift[0];
    s = fminf(fmaxf(s, -8.0f), 0.0f);
    const float scale   = exp2f(rintf(s));
    const float negtwos = -2.0f * scale;
    const float basev   = (float)IN_F * scale;

    const float4* xr = (const float4*)x;

    // two row slots in flight (depth-2 prefetch)
    float4 a[2][2];
    a[0][0] = xr[(size_t)row_base * 128 + lane];
    a[0][1] = xr[(size_t)row_base * 128 + 64 + lane];
    a[1][0] = xr[(size_t)(row_base + 2048) * 128 + lane];
    a[1][1] = xr[(size_t)(row_base + 2048) * 128 + 64 + lane];

#pragma unroll
    for (int j = 0; j < 16; ++j) {
        const int slot = j & 1;
        const int row  = row_base + j * 2048;

        // 1) ballot-pack row j -> wave-uniform words (frees slot's VGPRs)
        uint32_t xw[KW];
        {
            unsigned long long m;
            m = __ballot(a[slot][0].x >= 0.0f); xw[0]  = (uint32_t)m; xw[1]  = (uint32_t)(m >> 32);
            m = __ballot(a[slot][0].y >= 0.0f); xw[2]  = (uint32_t)m; xw[3]  = (uint32_t)(m >> 32);
            m = __ballot(a[slot][0].z >= 0.0f); xw[4]  = (uint32_t)m; xw[5]  = (uint32_t)(m >> 32);
            m = __ballot(a[slot][0].w >= 0.0f); xw[6]  = (uint32_t)m; xw[7]  = (uint32_t)(m >> 32);
            m = __ballot(a[slot][1].x >= 0.0f); xw[8]  = (uint32_t)m; xw[9]  = (uint32_t)(m >> 32);
            m = __ballot(a[slot][1].y >= 0.0f); xw[10] = (uint32_t)m; xw[11] = (uint32_t)(m >> 32);
            m = __ballot(a[slot][1].z >= 0.0f); xw[12] = (uint32_t)m; xw[13] = (uint32_t)(m >> 32);
            m = __ballot(a[slot][1].w >= 0.0f); xw[14] = (uint32_t)m; xw[15] = (uint32_t)(m >> 32);
        }

        // 2) issue depth-2 prefetch of row j+2 into the freed slot
        if (j < 14) {
            const size_t nb = (size_t)(row + 4096) * 128;
            a[slot][0] = xr[nb + lane];
            a[slot][1] = xr[nb + 64 + lane];
        }

        // 3) XOR + popcount accumulate (wave-uniform xw vs per-lane wv)
        uint32_t acc0 = 0, acc1 = 0, acc2 = 0, acc3 = 0;
#pragma unroll
        for (int k = 0; k < KW; ++k) {
            acc0 += __popc(xw[k] ^ wv[k][0]);
            acc1 += __popc(xw[k] ^ wv[k][1]);
            acc2 += __popc(xw[k] ^ wv[k][2]);
            acc3 += __popc(xw[k] ^ wv[k][3]);
        }

        // 4) (512 - 2*acc) * scale, exact in fp32; PLAIN store (A/B vs NT)
        f32x4 o4;
        o4.x = fmaf(negtwos, (float)acc0, basev);
        o4.y = fmaf(negtwos, (float)acc1, basev);
        o4.z = fmaf(negtwos, (float)acc2, basev);
        o4.w = fmaf(negtwos, (float)acc3, basev);
        *(f32x4*)&out[(size_t)row * OUT_F + og * 256 + lane * 4] = o4;
    }
}

extern "C" void kernel_launch(void* const* d_in, const int* in_sizes, int n_in,
                              void* d_out, int out_size, void* d_ws, size_t ws_size,
                              hipStream_t stream) {
    const float* x     = (const float*)d_in[0];
    const float* w     = (const float*)d_in[1];
    const float* thr   = (const float*)d_in[2];
    const float* shift = (const float*)d_in[3];
    float*       out   = (float*)d_out;
    uint32_t*    wbT   = (uint32_t*)d_ws;   // 16*512*4 = 32 KB scratch

    binw_kernel<<<128, 256, 0, stream>>>(w, thr, wbT);
    bgemm_kernel<<<1024, 256, 0, stream>>>(x, wbT, shift, out);
}

// Round 10
// 33.339 us; speedup vs baseline: 1.2128x; 1.0484x over previous
//
#include <hip/hip_runtime.h>
#include <stdint.h>

#define TOKENS 32768
#define IN_F   512
#define OUT_F  512
#define KW     16          // 512 bits -> 16 u32 words per row

typedef float f32x4 __attribute__((ext_vector_type(4)));

// ---------------------------------------------------------------------------
// Bit-packing permutation (identical in both kernels, so XOR+popc dot
// products are unaffected): from a row read as float4[128] (index f, lane l),
// word k = f_hi*8 + c*2 + h holds in bit l the sign of float4 #(f_hi*64+l)
// element c (h selects lanes 0..31 / 32..63).
// ---------------------------------------------------------------------------

// Kernel A: binarize weight (minus per-row threshold) into transposed
// bit-plane layout wbT[k][o]. TWO waves per output row (one half-row each):
// 1024 waves / 256 blocks so all 256 CUs participate (was 512 waves/64 CUs).
__global__ __launch_bounds__(256) void binw_kernel(
    const float* __restrict__ w,      // [OUT_F][IN_F]
    const float* __restrict__ thr,    // [OUT_F]
    uint32_t* __restrict__ wbT)       // [KW][OUT_F]
{
    const int g    = (blockIdx.x * 256 + threadIdx.x) >> 6;  // 1024 waves
    const int o    = g >> 1;          // output row
    const int h    = g & 1;           // which half of the row (float4 group)
    const int lane = threadIdx.x & 63;

    const float t = thr[o];
    const float4* wr = (const float4*)(w + (size_t)o * IN_F);
    float4 v = wr[h * 64 + lane];
    float vals[4] = {v.x - t, v.y - t, v.z - t, v.w - t};
#pragma unroll
    for (int c = 0; c < 4; ++c) {
        unsigned long long m = __ballot(vals[c] >= 0.0f);
        if (lane == 0) {
            wbT[(h * 8 + c * 2 + 0) * OUT_F + o] = (uint32_t)m;
            wbT[(h * 8 + c * 2 + 1) * OUT_F + o] = (uint32_t)(m >> 32);
        }
    }
}

// ---------------------------------------------------------------------------
// Kernel B: fused binarize-x + binary GEMM, weight bits resident in VGPRs.
// Round-4 structure verbatim (best measured: 33.1 us e2e). Wave gw owns
// og = gw&1 (256 cols, lane -> 4 cols) and rows row_base + j*2048, j=0..15.
// Depth-2 prefetch; non-temporal stores (A/B-verified +1.8 us vs plain).
// ---------------------------------------------------------------------------
__global__ __launch_bounds__(256, 4) void bgemm_kernel(
    const float*    __restrict__ x,     // [TOKENS][IN_F]
    const uint32_t* __restrict__ wbT,   // [KW][OUT_F]
    const float*    __restrict__ shift, // [1]
    float*          __restrict__ out)   // [TOKENS][OUT_F]
{
    const int lane = threadIdx.x & 63;
    const int wid  = threadIdx.x >> 6;
    const int gw   = blockIdx.x * 4 + wid;      // 0..4095
    const int og   = gw & 1;
    const int row_base = gw >> 1;               // 0..2047

    // --- weight bits for this wave's 256 columns: 64 VGPRs, loaded once ---
    uint32_t wv[KW][4];
    const uint32_t* wp = wbT + og * 256 + lane * 4;
#pragma unroll
    for (int k = 0; k < KW; ++k) {
        uint4 v = *(const uint4*)(wp + k * OUT_F);
        wv[k][0] = v.x; wv[k][1] = v.y; wv[k][2] = v.z; wv[k][3] = v.w;
    }

    // scale = 2^round(clip(shift, -8, 0)), round-half-even == rintf
    float s = shift[0];
    s = fminf(fmaxf(s, -8.0f), 0.0f);
    const float scale   = exp2f(rintf(s));
    const float negtwos = -2.0f * scale;
    const float basev   = (float)IN_F * scale;

    const float4* xr = (const float4*)x;

    // two row slots in flight (depth-2 prefetch)
    float4 a[2][2];
    a[0][0] = xr[(size_t)row_base * 128 + lane];
    a[0][1] = xr[(size_t)row_base * 128 + 64 + lane];
    a[1][0] = xr[(size_t)(row_base + 2048) * 128 + lane];
    a[1][1] = xr[(size_t)(row_base + 2048) * 128 + 64 + lane];

#pragma unroll
    for (int j = 0; j < 16; ++j) {
        const int slot = j & 1;
        const int row  = row_base + j * 2048;

        // 1) ballot-pack row j -> wave-uniform words (frees slot's VGPRs)
        uint32_t xw[KW];
        {
            unsigned long long m;
            m = __ballot(a[slot][0].x >= 0.0f); xw[0]  = (uint32_t)m; xw[1]  = (uint32_t)(m >> 32);
            m = __ballot(a[slot][0].y >= 0.0f); xw[2]  = (uint32_t)m; xw[3]  = (uint32_t)(m >> 32);
            m = __ballot(a[slot][0].z >= 0.0f); xw[4]  = (uint32_t)m; xw[5]  = (uint32_t)(m >> 32);
            m = __ballot(a[slot][0].w >= 0.0f); xw[6]  = (uint32_t)m; xw[7]  = (uint32_t)(m >> 32);
            m = __ballot(a[slot][1].x >= 0.0f); xw[8]  = (uint32_t)m; xw[9]  = (uint32_t)(m >> 32);
            m = __ballot(a[slot][1].y >= 0.0f); xw[10] = (uint32_t)m; xw[11] = (uint32_t)(m >> 32);
            m = __ballot(a[slot][1].z >= 0.0f); xw[12] = (uint32_t)m; xw[13] = (uint32_t)(m >> 32);
            m = __ballot(a[slot][1].w >= 0.0f); xw[14] = (uint32_t)m; xw[15] = (uint32_t)(m >> 32);
        }

        // 2) issue depth-2 prefetch of row j+2 into the freed slot
        if (j < 14) {
            const size_t nb = (size_t)(row + 4096) * 128;
            a[slot][0] = xr[nb + lane];
            a[slot][1] = xr[nb + 64 + lane];
        }

        // 3) XOR + popcount accumulate (wave-uniform xw vs per-lane wv)
        uint32_t acc0 = 0, acc1 = 0, acc2 = 0, acc3 = 0;
#pragma unroll
        for (int k = 0; k < KW; ++k) {
            acc0 += __popc(xw[k] ^ wv[k][0]);
            acc1 += __popc(xw[k] ^ wv[k][1]);
            acc2 += __popc(xw[k] ^ wv[k][2]);
            acc3 += __popc(xw[k] ^ wv[k][3]);
        }

        // 4) (512 - 2*acc) * scale, exact in fp32; non-temporal store
        f32x4 o4;
        o4.x = fmaf(negtwos, (float)acc0, basev);
        o4.y = fmaf(negtwos, (float)acc1, basev);
        o4.z = fmaf(negtwos, (float)acc2, basev);
        o4.w = fmaf(negtwos, (float)acc3, basev);
        __builtin_nontemporal_store(o4,
            (f32x4*)&out[(size_t)row * OUT_F + og * 256 + lane * 4]);
    }
}

extern "C" void kernel_launch(void* const* d_in, const int* in_sizes, int n_in,
                              void* d_out, int out_size, void* d_ws, size_t ws_size,
                              hipStream_t stream) {
    const float* x     = (const float*)d_in[0];
    const float* w     = (const float*)d_in[1];
    const float* thr   = (const float*)d_in[2];
    const float* shift = (const float*)d_in[3];
    float*       out   = (float*)d_out;
    uint32_t*    wbT   = (uint32_t*)d_ws;   // 16*512*4 = 32 KB scratch

    binw_kernel<<<256, 256, 0, stream>>>(w, thr, wbT);
    bgemm_kernel<<<1024, 256, 0, stream>>>(x, wbT, shift, out);
}

// Round 11
// 33.297 us; speedup vs baseline: 1.2143x; 1.0013x over previous
//
#include <hip/hip_runtime.h>
#include <stdint.h>

#define TOKENS 32768
#define IN_F   512
#define OUT_F  512
#define KW     16          // 512 bits -> 16 u32 words per row

typedef float f32x4 __attribute__((ext_vector_type(4)));

// ---------------------------------------------------------------------------
// Bit-packing permutation (identical in both kernels, so XOR+popc dot
// products are unaffected): from a row read as float4[128] (index f, lane l),
// word k = f_hi*8 + c*2 + h holds in bit l the sign of float4 #(f_hi*64+l)
// element c (h selects lanes 0..31 / 32..63).
// ---------------------------------------------------------------------------

// Kernel A: binarize weight (minus per-row threshold) into transposed
// bit-plane layout wbT[k][o]. Two waves per output row (one half-row each).
__global__ __launch_bounds__(256) void binw_kernel(
    const float* __restrict__ w,      // [OUT_F][IN_F]
    const float* __restrict__ thr,    // [OUT_F]
    uint32_t* __restrict__ wbT)       // [KW][OUT_F]
{
    const int g    = (blockIdx.x * 256 + threadIdx.x) >> 6;  // 1024 waves
    const int o    = g >> 1;          // output row
    const int h    = g & 1;           // which half of the row
    const int lane = threadIdx.x & 63;

    const float t = thr[o];
    const float4* wr = (const float4*)(w + (size_t)o * IN_F);
    float4 v = wr[h * 64 + lane];
    float vals[4] = {v.x - t, v.y - t, v.z - t, v.w - t};
#pragma unroll
    for (int c = 0; c < 4; ++c) {
        unsigned long long m = __ballot(vals[c] >= 0.0f);
        if (lane == 0) {
            wbT[(h * 8 + c * 2 + 0) * OUT_F + o] = (uint32_t)m;
            wbT[(h * 8 + c * 2 + 1) * OUT_F + o] = (uint32_t)(m >> 32);
        }
    }
}

// ---------------------------------------------------------------------------
// Kernel B: fused binarize-x + binary GEMM, weight bits resident in VGPRs.
// Round-4 structure, single change: DEPTH-3 prefetch (3 row slots) so the
// issue->consume distance (~870 cyc of VALU) covers the ~900 cyc HBM miss
// latency on the ~50% of x loads that miss L3 (FETCH=33MB of 64MB x-read).
// Wave gw owns og = gw&1 (256 cols, lane -> 4 cols) and rows
// row_base + j*2048, j=0..15. Non-temporal stores (A/B-verified win).
// ---------------------------------------------------------------------------
__global__ __launch_bounds__(256, 4) void bgemm_kernel(
    const float*    __restrict__ x,     // [TOKENS][IN_F]
    const uint32_t* __restrict__ wbT,   // [KW][OUT_F]
    const float*    __restrict__ shift, // [1]
    float*          __restrict__ out)   // [TOKENS][OUT_F]
{
    const int lane = threadIdx.x & 63;
    const int wid  = threadIdx.x >> 6;
    const int gw   = blockIdx.x * 4 + wid;      // 0..4095
    const int og   = gw & 1;
    const int row_base = gw >> 1;               // 0..2047

    // --- weight bits for this wave's 256 columns: 64 VGPRs, loaded once ---
    uint32_t wv[KW][4];
    const uint32_t* wp = wbT + og * 256 + lane * 4;
#pragma unroll
    for (int k = 0; k < KW; ++k) {
        uint4 v = *(const uint4*)(wp + k * OUT_F);
        wv[k][0] = v.x; wv[k][1] = v.y; wv[k][2] = v.z; wv[k][3] = v.w;
    }

    // scale = 2^round(clip(shift, -8, 0)), round-half-even == rintf
    float s = shift[0];
    s = fminf(fmaxf(s, -8.0f), 0.0f);
    const float scale   = exp2f(rintf(s));
    const float negtwos = -2.0f * scale;
    const float basev   = (float)IN_F * scale;

    const float4* xr = (const float4*)x;

    // THREE row slots in flight (depth-3 prefetch)
    float4 a[3][2];
#pragma unroll
    for (int p = 0; p < 3; ++p) {
        const size_t rb = (size_t)(row_base + p * 2048) * 128;
        a[p][0] = xr[rb + lane];
        a[p][1] = xr[rb + 64 + lane];
    }

#pragma unroll
    for (int j = 0; j < 16; ++j) {
        const int slot = j % 3;                 // static after full unroll
        const int row  = row_base + j * 2048;

        // 1) ballot-pack row j -> wave-uniform words (frees slot's VGPRs)
        uint32_t xw[KW];
        {
            unsigned long long m;
            m = __ballot(a[slot][0].x >= 0.0f); xw[0]  = (uint32_t)m; xw[1]  = (uint32_t)(m >> 32);
            m = __ballot(a[slot][0].y >= 0.0f); xw[2]  = (uint32_t)m; xw[3]  = (uint32_t)(m >> 32);
            m = __ballot(a[slot][0].z >= 0.0f); xw[4]  = (uint32_t)m; xw[5]  = (uint32_t)(m >> 32);
            m = __ballot(a[slot][0].w >= 0.0f); xw[6]  = (uint32_t)m; xw[7]  = (uint32_t)(m >> 32);
            m = __ballot(a[slot][1].x >= 0.0f); xw[8]  = (uint32_t)m; xw[9]  = (uint32_t)(m >> 32);
            m = __ballot(a[slot][1].y >= 0.0f); xw[10] = (uint32_t)m; xw[11] = (uint32_t)(m >> 32);
            m = __ballot(a[slot][1].z >= 0.0f); xw[12] = (uint32_t)m; xw[13] = (uint32_t)(m >> 32);
            m = __ballot(a[slot][1].w >= 0.0f); xw[14] = (uint32_t)m; xw[15] = (uint32_t)(m >> 32);
        }

        // 2) issue depth-3 prefetch of row j+3 into the freed slot
        if (j < 13) {
            const size_t nb = (size_t)(row + 3 * 2048) * 128;
            a[slot][0] = xr[nb + lane];
            a[slot][1] = xr[nb + 64 + lane];
        }

        // 3) XOR + popcount accumulate (wave-uniform xw vs per-lane wv)
        uint32_t acc0 = 0, acc1 = 0, acc2 = 0, acc3 = 0;
#pragma unroll
        for (int k = 0; k < KW; ++k) {
            acc0 += __popc(xw[k] ^ wv[k][0]);
            acc1 += __popc(xw[k] ^ wv[k][1]);
            acc2 += __popc(xw[k] ^ wv[k][2]);
            acc3 += __popc(xw[k] ^ wv[k][3]);
        }

        // 4) (512 - 2*acc) * scale, exact in fp32; non-temporal store
        f32x4 o4;
        o4.x = fmaf(negtwos, (float)acc0, basev);
        o4.y = fmaf(negtwos, (float)acc1, basev);
        o4.z = fmaf(negtwos, (float)acc2, basev);
        o4.w = fmaf(negtwos, (float)acc3, basev);
        __builtin_nontemporal_store(o4,
            (f32x4*)&out[(size_t)row * OUT_F + og * 256 + lane * 4]);
    }
}

extern "C" void kernel_launch(void* const* d_in, const int* in_sizes, int n_in,
                              void* d_out, int out_size, void* d_ws, size_t ws_size,
                              hipStream_t stream) {
    const float* x     = (const float*)d_in[0];
    const float* w     = (const float*)d_in[1];
    const float* thr   = (const float*)d_in[2];
    const float* shift = (const float*)d_in[3];
    float*       out   = (float*)d_out;
    uint32_t*    wbT   = (uint32_t*)d_ws;   // 16*512*4 = 32 KB scratch

    binw_kernel<<<256, 256, 0, stream>>>(w, thr, wbT);
    bgemm_kernel<<<1024, 256, 0, stream>>>(x, wbT, shift, out);
}